// Round 15
// baseline (195.998 us; speedup 1.0000x reference)
//
#include <hip/hip_runtime.h>

#define BATCH 2048
#define DIM   256
#define WAVES 8   // 512 threads/block
#define RT    2   // batch 16-tiles per wave

typedef _Float16 half4 __attribute__((ext_vector_type(4)));
typedef __attribute__((ext_vector_type(4))) float f32x4;

// K=16 transposed chain: activations stay in registers as H^T tiles whose
// MFMA C/D layout (row=q*4+r, col=m) IS the B-operand layout (k=q*4+j, n=m)
// of v_mfma_f32_16x16x16_f16. Weights are A-operands from LDS.
// 16x16 weight-tile table (g = FO/16-block, f = FI/16-block),
// tile index = BASE + g*KT + f:
//   L1(32->64):  base 0,  KT=2, GT=4  (8 tiles)
//   L2(64->128): base 8,  KT=4, GT=8  (32)
//   L3(128->64): base 40, KT=8, GT=4  (32)
//   L4(64->32):  base 72, KT=4, GT=2  (8)
//   L5(32->16):  base 80, KT=2, GT=1  (2)
#define NT16 82
#define TILE16_HALVES 256   // 64 lanes * 4 halves = 512 B
// LDS float strip: biases L1@0(64) L2@64(128) L3@192(64) L4@256(32) L5@288(16)
// then W0@304(32), b0@336(32), W6@368(16) -> 384 floats total.
#define STRIP_FLOATS 384

// One layer: D[rt][g] = sum_f A(g,f) * Bin[rt][f] + bias; A from LDS.
// SIN/SOUT: rt-strides of the register arrays (Ba stride 8, Bb stride 4) --
// right-sizing these is what keeps peak live regs < 128 (R14 spilled at
// [RT][8] x2 + hoisted params).
template <int KT, int GT, int TBASE, int BOFF, int SIN, int SOUT, bool EXTRACT>
__device__ __forceinline__ void layer16(
    const _Float16* __restrict__ packs, const float* __restrict__ strip,
    int q, int lane, const half4* Bin, half4* Bout, f32x4* Dout) {
#pragma unroll
  for (int g = 0; g < GT; ++g) {
    const f32x4 bias4 = *(const f32x4*)(strip + BOFF + g * 16 + q * 4);
    f32x4 acc[RT];
#pragma unroll
    for (int rt = 0; rt < RT; ++rt) acc[rt] = bias4;
#pragma unroll
    for (int f = 0; f < KT; ++f) {
      const half4 w =
          *(const half4*)(packs + (TBASE + g * KT + f) * TILE16_HALVES + lane * 4);
#pragma unroll
      for (int rt = 0; rt < RT; ++rt)
        acc[rt] =
            __builtin_amdgcn_mfma_f32_16x16x16f16(w, Bin[rt * SIN + f], acc[rt], 0, 0, 0);
    }
#pragma unroll
    for (int rt = 0; rt < RT; ++rt) {
      if (EXTRACT) {
        half4 o;
#pragma unroll
        for (int r = 0; r < 4; ++r) o[r] = (_Float16)fmaxf(acc[rt][r], 0.0f);
        Bout[rt * SOUT + g] = o;
      } else {
        f32x4 v;
#pragma unroll
        for (int r = 0; r < 4; ++r) v[r] = fmaxf(acc[rt][r], 0.0f);  // L5 ReLU
        Dout[rt] = v;
      }
    }
  }
}

// Fused kernel: grid (256 d, 2 batch-halves), 512 threads. Phase 1: pack
// W1..W5[d] (A-frag order, f16) + bias/W0/b0/W6 strip into LDS (43520 B ->
// 2 blocks/CU by the 16-waves VGPR cap). Phase 2: 4 iters x 8 waves x 32 rows;
// activations never touch LDS (register MFMA chain).
// NOTE R10: launch_bounds(512,4) forced 64 VGPR + spill. R12: atomics +34us.
// R13: cooperative launch never ran. R14: [RT][8]x2 arrays + hoisted params
// -> 128-VGPR spill, 258 MB scratch traffic.
__global__ __launch_bounds__(512, 2) void mlp_fused(
    const float* __restrict__ x,
    const float* __restrict__ W0, const float* __restrict__ b0,
    const float* __restrict__ W1, const float* __restrict__ b1,
    const float* __restrict__ W2, const float* __restrict__ b2,
    const float* __restrict__ W3, const float* __restrict__ b3,
    const float* __restrict__ W4, const float* __restrict__ b4,
    const float* __restrict__ W5, const float* __restrict__ b5,
    const float* __restrict__ W6, const float* __restrict__ b6,
    float* __restrict__ partial) {
  const int t = threadIdx.x;
  const int lane = t & 63;
  const int wave = t >> 6;
  const int m = lane & 15, q = lane >> 4;
  const int d = blockIdx.x;
  const int bh = blockIdx.y;

  __shared__ __align__(16) _Float16 packs[NT16 * TILE16_HALVES];  // 41984 B
  __shared__ __align__(16) float strip[STRIP_FLOATS];             // 1536 B

  // ---- phase 1a: weights -> LDS in A-frag order ----
  // A(g,f)[m=jm][k=jq*4+j] = W[d][16f + jq*4 + j][16g + jm]
  for (int job = t; job < NT16 * 64; job += 512) {
    const int tile = job >> 6, jl = job & 63;
    const int jm = jl & 15, jq = jl >> 4;
    const float* W; int FI, FO, lt;
    if (tile < 8)       { W = W1; FI = 32;  FO = 64;  lt = tile; }
    else if (tile < 40) { W = W2; FI = 64;  FO = 128; lt = tile - 8; }
    else if (tile < 72) { W = W3; FI = 128; FO = 64;  lt = tile - 40; }
    else if (tile < 80) { W = W4; FI = 64;  FO = 32;  lt = tile - 72; }
    else                { W = W5; FI = 32;  FO = 16;  lt = tile - 80; }
    const int KT = FI >> 4;
    const int g = lt / KT, f = lt - g * KT;
    const float* Wp = W + (size_t)d * FI * FO + (size_t)(16 * f + jq * 4) * FO +
                      16 * g + jm;
    half4 w;
#pragma unroll
    for (int j = 0; j < 4; ++j) w[j] = (_Float16)Wp[(size_t)j * FO];
    *(half4*)(packs + (size_t)tile * TILE16_HALVES + jl * 4) = w;
  }
  // ---- phase 1b: bias + L0/L6 param strip -> LDS ----
  if (t < STRIP_FLOATS) {
    float v;
    if (t < 64)       v = b1[d * 64 + t];
    else if (t < 192) v = b2[d * 128 + (t - 64)];
    else if (t < 256) v = b3[d * 64 + (t - 192)];
    else if (t < 288) v = b4[d * 32 + (t - 256)];
    else if (t < 304) v = b5[d * 16 + (t - 288)];
    else if (t < 336) v = W0[d * 32 + (t - 304)];
    else if (t < 368) v = b0[d * 32 + (t - 336)];
    else              v = W6[d * 16 + (t - 368)];
    strip[t] = v;
  }
  const float bias6 = b6[d];

  __syncthreads();   // pack + strip ready; the ONLY barrier

  half4 Ba[RT * 8], Bb[RT * 4];
  f32x4 D5[RT];

  // ---- phase 2: 4 iterations x (8 waves * RT*16 rows) ----
  for (int it = 0; it < 4; ++it) {
    const int row0 = bh * 1024 + it * 256 + wave * 32;

    // L0: 1 -> 32. B1-frag[f][j] = relu(x[b]*W0[16f+q*4+j]+b0[...]), b = m.
    // W0/b0 read from the LDS strip (16-lane broadcast -> conflict-free).
#pragma unroll
    for (int rt = 0; rt < RT; ++rt) {
      const float xv = x[(size_t)(row0 + rt * 16 + m) * DIM + d];
#pragma unroll
      for (int f = 0; f < 2; ++f) {
        const f32x4 w0v = *(const f32x4*)(strip + 304 + f * 16 + q * 4);
        const f32x4 b0v = *(const f32x4*)(strip + 336 + f * 16 + q * 4);
        half4 o;
#pragma unroll
        for (int j = 0; j < 4; ++j)
          o[j] = (_Float16)fmaxf(fmaf(xv, w0v[j], b0v[j]), 0.0f);
        Ba[rt * 8 + f] = o;
      }
    }

    layer16<2, 4, 0, 0, 8, 4, true>(packs, strip, q, lane, Ba, Bb, nullptr);    // L1
    layer16<4, 8, 8, 64, 4, 8, true>(packs, strip, q, lane, Bb, Ba, nullptr);   // L2
    layer16<8, 4, 40, 192, 8, 4, true>(packs, strip, q, lane, Ba, Bb, nullptr); // L3
    layer16<4, 2, 72, 256, 4, 8, true>(packs, strip, q, lane, Bb, Ba, nullptr); // L4
    layer16<2, 1, 80, 288, 8, 4, false>(packs, strip, q, lane, Ba, Bb, D5);     // L5

    // L6: 16 -> 1. D5[rt] reg r = H6^T[q*4+r][m]; dot with W6, sum over q.
    {
      const f32x4 w6v = *(const f32x4*)(strip + 368 + q * 4);
#pragma unroll
      for (int rt = 0; rt < RT; ++rt) {
        float v = 0.0f;
#pragma unroll
        for (int r = 0; r < 4; ++r) v = fmaf(w6v[r], D5[rt][r], v);
        v += __shfl_xor(v, 16);
        v += __shfl_xor(v, 32);
        if (lane < 16)
          partial[(size_t)d * BATCH + row0 + rt * 16 + m] = v + bias6;
      }
    }
  }
}

__global__ __launch_bounds__(256) void reduce_kernel(
    const float* __restrict__ partial, float* __restrict__ out) {
  const int b = blockIdx.x * blockDim.x + threadIdx.x;
  float s = 0.0f;
#pragma unroll 8
  for (int d = 0; d < DIM; ++d) s += partial[(size_t)d * BATCH + b];
  out[b] = s;
}

extern "C" void kernel_launch(void* const* d_in, const int* in_sizes, int n_in,
                              void* d_out, int out_size, void* d_ws, size_t ws_size,
                              hipStream_t stream) {
  const float* x = (const float*)d_in[0];
  const float* W[7];
  const float* B[7];
  for (int l = 0; l < 7; ++l) {
    W[l] = (const float*)d_in[1 + 2 * l];
    B[l] = (const float*)d_in[2 + 2 * l];
  }
  float* partial = (float*)d_ws;  // 2 MB

  mlp_fused<<<dim3(DIM, 2), dim3(512), 0, stream>>>(
      x, W[0], B[0], W[1], B[1], W[2], B[2], W[3], B[3], W[4], B[4], W[5], B[5],
      W[6], B[6], partial);

  reduce_kernel<<<dim3(BATCH / 256), dim3(256), 0, stream>>>(partial,
                                                             (float*)d_out);
}

// Round 16
// 190.054 us; speedup vs baseline: 1.0313x; 1.0313x over previous
//
#include <hip/hip_runtime.h>

#define BATCH 2048
#define DIM   256
#define WAVES 8   // 512 threads/block

typedef _Float16 half4 __attribute__((ext_vector_type(4)));
typedef __attribute__((ext_vector_type(4))) float f32x4;

// K=16 transposed chain: activations stay in registers as H^T tiles whose
// MFMA C/D layout (row=q*4+r, col=m) IS the B-operand layout (k=q*4+j, n=m)
// of v_mfma_f32_16x16x16_f16. Weights are A-operands from LDS.
// 16x16 weight-tile table (g = FO/16-block, f = FI/16-block),
// tile index = BASE + g*KT + f:
//   L1(32->64):  base 0,  KT=2, GT=4  (8 tiles)
//   L2(64->128): base 8,  KT=4, GT=8  (32)
//   L3(128->64): base 40, KT=8, GT=4  (32)
//   L4(64->32):  base 72, KT=4, GT=2  (8)
//   L5(32->16):  base 80, KT=2, GT=1  (2)
#define NT16 82
#define TILE16_HALVES 256   // 64 lanes * 4 halves = 512 B
// LDS float strip: biases L1@0(64) L2@64(128) L3@192(64) L4@256(32) L5@288(16)
// then W0@304(32), b0@336(32), W6@368(16) -> 384 floats.
#define STRIP_FLOATS 384

// One dense layer of the chain, expanded IN KERNEL SCOPE (no pointer-passed
// frag arrays -- R14/R15 materialized them in scratch: 128 VGPR + ~160 MB
// scratch traffic). IN/OUT are local 2D arrays, all indices constant.
#define LAYER16(KT, GT, TBASE, BOFF, IN, OUT)                                 \
  _Pragma("unroll") for (int g = 0; g < GT; ++g) {                            \
    const f32x4 bias4 = *(const f32x4*)(strip + (BOFF) + g * 16 + q * 4);     \
    f32x4 acc0 = bias4, acc1 = bias4;                                         \
    _Pragma("unroll") for (int f = 0; f < KT; ++f) {                          \
      const half4 w = *(const half4*)(packs +                                 \
          ((TBASE) + g * (KT) + f) * TILE16_HALVES + lane * 4);               \
      acc0 = __builtin_amdgcn_mfma_f32_16x16x16f16(w, IN[0][f], acc0, 0, 0, 0);\
      acc1 = __builtin_amdgcn_mfma_f32_16x16x16f16(w, IN[1][f], acc1, 0, 0, 0);\
    }                                                                         \
    _Pragma("unroll") for (int r = 0; r < 4; ++r) {                           \
      OUT[0][g][r] = (_Float16)fmaxf(acc0[r], 0.0f);                          \
      OUT[1][g][r] = (_Float16)fmaxf(acc1[r], 0.0f);                          \
    }                                                                         \
  }

// Fused kernel: grid (256 d, 2 batch-halves), 512 threads. Phase 1: pack
// W1..W5[d] (A-frag order, f16) + bias/W0/b0/W6 strip into LDS (43520 B ->
// 2 blocks/CU). Phase 2: 4 iters x 8 waves x 32 rows; activations live in
// registers only (zero LDS traffic for acts).
// NOTE R10: launch_bounds(512,4) -> 64-VGPR squeeze + spill. R12: atomics
// +34us. R13: cooperative launch never ran. R14/R15: frag arrays passed by
// pointer through layer fn -> scratch-materialized (128 VGPR, 178 MB FETCH).
__global__ __launch_bounds__(512, 2) void mlp_fused(
    const float* __restrict__ x,
    const float* __restrict__ W0, const float* __restrict__ b0,
    const float* __restrict__ W1, const float* __restrict__ b1,
    const float* __restrict__ W2, const float* __restrict__ b2,
    const float* __restrict__ W3, const float* __restrict__ b3,
    const float* __restrict__ W4, const float* __restrict__ b4,
    const float* __restrict__ W5, const float* __restrict__ b5,
    const float* __restrict__ W6, const float* __restrict__ b6,
    float* __restrict__ partial) {
  const int t = threadIdx.x;
  const int lane = t & 63;
  const int wave = t >> 6;
  const int m = lane & 15, q = lane >> 4;
  const int d = blockIdx.x;
  const int bh = blockIdx.y;

  __shared__ __align__(16) _Float16 packs[NT16 * TILE16_HALVES];  // 41984 B
  __shared__ __align__(16) float strip[STRIP_FLOATS];             // 1536 B

  // ---- phase 1a: weights -> LDS in A-frag order ----
  // A(g,f)[m=jm][k=jq*4+j] = W[d][16f + jq*4 + j][16g + jm]
  for (int job = t; job < NT16 * 64; job += 512) {
    const int tile = job >> 6, jl = job & 63;
    const int jm = jl & 15, jq = jl >> 4;
    const float* W; int FI, FO, lt;
    if (tile < 8)       { W = W1; FI = 32;  FO = 64;  lt = tile; }
    else if (tile < 40) { W = W2; FI = 64;  FO = 128; lt = tile - 8; }
    else if (tile < 72) { W = W3; FI = 128; FO = 64;  lt = tile - 40; }
    else if (tile < 80) { W = W4; FI = 64;  FO = 32;  lt = tile - 72; }
    else                { W = W5; FI = 32;  FO = 16;  lt = tile - 80; }
    const int KT = FI >> 4;
    const int g = lt / KT, f = lt - g * KT;
    const float* Wp = W + (size_t)d * FI * FO + (size_t)(16 * f + jq * 4) * FO +
                      16 * g + jm;
    half4 w;
#pragma unroll
    for (int j = 0; j < 4; ++j) w[j] = (_Float16)Wp[(size_t)j * FO];
    *(half4*)(packs + (size_t)tile * TILE16_HALVES + jl * 4) = w;
  }
  // ---- phase 1b: bias + L0/L6 param strip -> LDS ----
  if (t < STRIP_FLOATS) {
    float v;
    if (t < 64)       v = b1[d * 64 + t];
    else if (t < 192) v = b2[d * 128 + (t - 64)];
    else if (t < 256) v = b3[d * 64 + (t - 192)];
    else if (t < 288) v = b4[d * 32 + (t - 256)];
    else if (t < 304) v = b5[d * 16 + (t - 288)];
    else if (t < 336) v = W0[d * 32 + (t - 304)];
    else if (t < 368) v = b0[d * 32 + (t - 336)];
    else              v = W6[d * 16 + (t - 368)];
    strip[t] = v;
  }
  const float bias6 = b6[d];

  __syncthreads();   // pack + strip ready; the ONLY barrier

  // ---- phase 2: 4 iterations x (8 waves * 32 rows) ----
#pragma unroll 1
  for (int it = 0; it < 4; ++it) {
    const int row0 = bh * 1024 + it * 256 + wave * 32;

    half4 A[2][8];   // fresh per iteration: no cross-iteration live ranges
    half4 B4[2][4];

    // L0: 1 -> 32. A[rt][f][j] = relu(x[b]*W0[16f+q*4+j]+b0), b = row0+rt*16+m.
#pragma unroll
    for (int rt = 0; rt < 2; ++rt) {
      const float xv = x[(size_t)(row0 + rt * 16 + m) * DIM + d];
#pragma unroll
      for (int f = 0; f < 2; ++f) {
        const f32x4 w0v = *(const f32x4*)(strip + 304 + f * 16 + q * 4);
        const f32x4 b0v = *(const f32x4*)(strip + 336 + f * 16 + q * 4);
#pragma unroll
        for (int j = 0; j < 4; ++j)
          A[rt][f][j] = (_Float16)fmaxf(fmaf(xv, w0v[j], b0v[j]), 0.0f);
      }
    }

    LAYER16(2, 4, 0, 0, A, B4)      // L1: 32->64
    LAYER16(4, 8, 8, 64, B4, A)     // L2: 64->128
    LAYER16(8, 4, 40, 192, A, B4)   // L3: 128->64
    LAYER16(4, 2, 72, 256, B4, A)   // L4: 64->32
    // L5 (32->16) + L6 (16->1) fused; L5 output kept in acc regs.
    {
      const f32x4 bias4 = *(const f32x4*)(strip + 288 + q * 4);
      const f32x4 w6v = *(const f32x4*)(strip + 368 + q * 4);
      f32x4 acc0 = bias4, acc1 = bias4;
#pragma unroll
      for (int f = 0; f < 2; ++f) {
        const half4 w =
            *(const half4*)(packs + (80 + f) * TILE16_HALVES + lane * 4);
        acc0 = __builtin_amdgcn_mfma_f32_16x16x16f16(w, A[0][f], acc0, 0, 0, 0);
        acc1 = __builtin_amdgcn_mfma_f32_16x16x16f16(w, A[1][f], acc1, 0, 0, 0);
      }
      float v0 = 0.0f, v1 = 0.0f;
#pragma unroll
      for (int r = 0; r < 4; ++r) {
        v0 = fmaf(w6v[r], fmaxf(acc0[r], 0.0f), v0);   // L5 ReLU + L6 dot
        v1 = fmaf(w6v[r], fmaxf(acc1[r], 0.0f), v1);
      }
      v0 += __shfl_xor(v0, 16); v0 += __shfl_xor(v0, 32);
      v1 += __shfl_xor(v1, 16); v1 += __shfl_xor(v1, 32);
      if (lane < 16) {
        partial[(size_t)d * BATCH + row0 + m] = v0 + bias6;
        partial[(size_t)d * BATCH + row0 + 16 + m] = v1 + bias6;
      }
    }
  }
}

__global__ __launch_bounds__(256) void reduce_kernel(
    const float* __restrict__ partial, float* __restrict__ out) {
  const int b = blockIdx.x * blockDim.x + threadIdx.x;
  float s = 0.0f;
#pragma unroll 8
  for (int d = 0; d < DIM; ++d) s += partial[(size_t)d * BATCH + b];
  out[b] = s;
}

extern "C" void kernel_launch(void* const* d_in, const int* in_sizes, int n_in,
                              void* d_out, int out_size, void* d_ws, size_t ws_size,
                              hipStream_t stream) {
  const float* x = (const float*)d_in[0];
  const float* W[7];
  const float* B[7];
  for (int l = 0; l < 7; ++l) {
    W[l] = (const float*)d_in[1 + 2 * l];
    B[l] = (const float*)d_in[2 + 2 * l];
  }
  float* partial = (float*)d_ws;  // 2 MB

  mlp_fused<<<dim3(DIM, 2), dim3(512), 0, stream>>>(
      x, W[0], B[0], W[1], B[1], W[2], B[2], W[3], B[3], W[4], B[4], W[5], B[5],
      W[6], B[6], partial);

  reduce_kernel<<<dim3(BATCH / 256), dim3(256), 0, stream>>>(partial,
                                                             (float*)d_out);
}